// Round 17
// baseline (1112.689 us; speedup 1.0000x reference)
//
#include <hip/hip_runtime.h>
#include <math.h>

// Shapes: B=32, C=256, H=W=64 (HW=4096), ch=64, ac=384
// h buffer lives in d_out.
// ws: xt_pad (32x64 planes, 68x68; image (r,c) -> padded (r+2,c+2); borders
// permanently zero) + temp (3 conv ops) + tempP (conv5 ic-half-1 partials) + stats.
// r17: conv inner loops restructured to issue ALL row-loads of an ic
// back-to-back before any FMA (RA/RB float4 arrays, compile-time indexed) --
// r16 disasm-by-counters showed the compiler's minimal 48-VGPR schedule
// exposes ~200cy L1 latency at each ic start (27% idle at 4 waves/SIMD).
// Live ~70 VGPR: safe under the (256,4) 128-cap (r5: 76 clean; r9 squeeze
// only when bound-cap < live).

#define PLANE 4624   // 68*68 floats per (b,ch) plane
#define PCOLS 68

__device__ __forceinline__ float wave_sum(float v){
#pragma unroll
    for (int o = 32; o; o >>= 1) v += __shfl_down(v, o, 64);
    return v;
}
__device__ __forceinline__ float wave_max(float v){
#pragma unroll
    for (int o = 32; o; o >>= 1) v = fmaxf(v, __shfl_down(v, o, 64));
    return v;
}

// K1: per-(b,c) spatial mean & max of relu(src) — round 1 only
__global__ __launch_bounds__(256) void k_meanmax(const float* __restrict__ src,
                                                 float* __restrict__ meanb,
                                                 float* __restrict__ maxb){
    int bc = blockIdx.x, t = threadIdx.x;
    const float4* p = (const float4*)(src + ((size_t)bc << 12));
    float s = 0.f, m = 0.f;
    for (int i = t; i < 1024; i += 256){
        float4 v = p[i];
        float a = fmaxf(v.x, 0.f), b = fmaxf(v.y, 0.f), c = fmaxf(v.z, 0.f), d = fmaxf(v.w, 0.f);
        s += (a + b) + (c + d);
        m = fmaxf(m, fmaxf(fmaxf(a, b), fmaxf(c, d)));
    }
    s = wave_sum(s); m = wave_max(m);
    __shared__ float ss[4], sm_[4];
    int lane = t & 63, w = t >> 6;
    if (!lane){ ss[w] = s; sm_[w] = m; }
    __syncthreads();
    if (!t){
        meanb[bc] = (ss[0] + ss[1] + ss[2] + ss[3]) * (1.f / 4096.f);
        maxb[bc]  = fmaxf(fmaxf(sm_[0], sm_[1]), fmaxf(sm_[2], sm_[3]));
    }
}

// K2: nl = sigmoid(mlp(mean)+mlp(max)); w1:(128,256), w2:(256,128)
__global__ __launch_bounds__(256) void k_nl(const float* __restrict__ meanb, const float* __restrict__ maxb,
                                            const float* __restrict__ w1, const float* __restrict__ w2,
                                            float* __restrict__ nl){
    int b = blockIdx.x, t = threadIdx.x;
    __shared__ float sm[256], sx[256], hid[128];
    sm[t] = meanb[b * 256 + t]; sx[t] = maxb[b * 256 + t];
    __syncthreads();
    if (t < 128){
        float a = 0.f, c = 0.f;
        const float* wr = w1 + t * 256;
        for (int k = 0; k < 256; ++k){ float w = wr[k]; a = fmaf(w, sm[k], a); c = fmaf(w, sx[k], c); }
        hid[t] = fmaxf(a, 0.f) + fmaxf(c, 0.f);   // relu(h_mean)+relu(h_max), second matmul is linear
    }
    __syncthreads();
    float o = 0.f;
    const float* wr = w2 + t * 128;
    for (int j = 0; j < 128; ++j) o = fmaf(wr[j], hid[j], o);
    nl[b * 256 + t] = 1.f / (1.f + expf(-o));
}

// K2b: slist = nl.sum(0); stable top-64; zeros tsum, bnsq2d for this round
__global__ __launch_bounds__(256) void k_topk(const float* __restrict__ nl,
                                              int* __restrict__ idx, int* __restrict__ selpos,
                                              float* __restrict__ tsum, float* __restrict__ bnsq2d){
    int t = threadIdx.x;
    for (int i = t; i < 12288; i += 256) tsum[i] = 0.f;
    for (int i = t; i < 4096; i += 256) bnsq2d[i] = 0.f;
    __shared__ float sl[256];
    float s = 0.f;
    for (int b = 0; b < 32; ++b) s += nl[b * 256 + t];
    sl[t] = s; __syncthreads();
    float mys = sl[t];
    int rank = 0;
    for (int c = 0; c < 256; ++c){ float v = sl[c]; rank += (v > mys) || (v == mys && c < t); }
    selpos[t] = (rank < 64) ? rank : -1;
    if (rank < 64) idx[rank] = t;
}

// K3: dst = relu(src)*nl (+x in round 2); gather selected into padded planes.
// sp>=0 blocks: stage padded plane in LDS, compute 3x3 pools inline, plain-
// store the 5 BN/op sums. Round-1 sp<0 blocks: stats for round 2's k_nl.
__global__ __launch_bounds__(256) void k_scale(const float* __restrict__ src, float* __restrict__ dst,
                                               float* __restrict__ xtp, const float* __restrict__ nl,
                                               const int* __restrict__ selpos, float* __restrict__ tsum,
                                               float* __restrict__ bnsq2d, const float* __restrict__ xadd,
                                               float* __restrict__ meanb, float* __restrict__ maxb){
    __shared__ float pl[PLANE];
    __shared__ float red[20];
    int bc = blockIdx.x, t = threadIdx.x;
    int b = bc >> 8, c = bc & 255;
    float sc = nl[bc];
    int sp = selpos[c];
    const float4* s4 = (const float4*)(src + ((size_t)bc << 12));
    float4* d4 = (float4*)(dst + ((size_t)bc << 12));
    const float4* a4 = xadd ? (const float4*)(xadd + ((size_t)bc << 12)) : (const float4*)nullptr;
    float* xp = (sp >= 0) ? (xtp + (size_t)(b * 64 + sp) * PLANE) : (float*)nullptr;

    if (sp >= 0){
        for (int i = t; i < PLANE; i += 256) pl[i] = 0.f;
        __syncthreads();
    }

    float st = 0.f, md = 0.f;
    for (int i = t; i < 1024; i += 256){
        float4 v = s4[i];
        v.x = fmaxf(v.x, 0.f) * sc; v.y = fmaxf(v.y, 0.f) * sc;
        v.z = fmaxf(v.z, 0.f) * sc; v.w = fmaxf(v.w, 0.f) * sc;
        st += (v.x + v.y) + (v.z + v.w);
        md = fmaxf(md, fmaxf(fmaxf(v.x, v.y), fmaxf(v.z, v.w)));
        if (sp >= 0){
            int off = ((i >> 4) + 2) * PCOLS + ((i & 15) << 2) + 2;
            float* w = xp + off;                 // 8B-aligned
            *(float2*)(w)     = make_float2(v.x, v.y);
            *(float2*)(w + 2) = make_float2(v.z, v.w);
            pl[off]     = v.x; pl[off + 1] = v.y;
            pl[off + 2] = v.z; pl[off + 3] = v.w;
        }
        float4 dv = v;
        if (a4){ float4 av = a4[i]; dv.x += av.x; dv.y += av.y; dv.z += av.z; dv.w += av.w; }
        d4[i] = dv;
    }

    int lane = t & 63, w = t >> 6;
    if (sp >= 0){
        __syncthreads();
        float sa = 0.f, sa2 = 0.f, smx = 0.f, smx2 = 0.f;
        for (int i = t; i < 1024; i += 256){
            int row = i >> 4, col0 = (i & 15) << 2;
#pragma unroll
            for (int px = 0; px < 4; ++px){
                int x = col0 + px;
                float s = 0.f, m = 0.f;
#pragma unroll
                for (int dy = 0; dy < 3; ++dy){
                    const float* q = pl + (row + 1 + dy) * PCOLS + x + 2;
                    float a = q[-1], bb = q[0], cc = q[1];
                    s += (a + bb) + cc;
                    m = fmaxf(m, fmaxf(fmaxf(a, bb), cc));
                }
                int cy = min(row + 1, 63) - max(row - 1, 0) + 1;
                int cx = min(x + 1, 63) - max(x - 1, 0) + 1;
                float av = s / (float)(cy * cx);
                sa += av; sa2 = fmaf(av, av, sa2);
                smx += m; smx2 = fmaf(m, m, smx2);
            }
        }
        float r0 = wave_sum(st), r1 = wave_sum(sa), r2 = wave_sum(sa2);
        float r3 = wave_sum(smx), r4 = wave_sum(smx2);
        if (!lane){ red[w] = r0; red[4 + w] = r1; red[8 + w] = r2; red[12 + w] = r3; red[16 + w] = r4; }
        __syncthreads();
        if (!t){
            tsum[b * 384 + 320 + sp] = red[0] + red[1] + red[2] + red[3];
            tsum[b * 384 + 192 + sp] = red[4] + red[5] + red[6] + red[7];
            bnsq2d[b * 128 + sp]     = red[8] + red[9] + red[10] + red[11];
            tsum[b * 384 + 256 + sp] = red[12] + red[13] + red[14] + red[15];
            bnsq2d[b * 128 + 64 + sp]= red[16] + red[17] + red[18] + red[19];
        }
    } else if (!xadd){
        // round 1, non-selected channel: dst is final h -> stats for round 2
        float r0 = wave_sum(st), r1 = wave_max(md);
        if (!lane){ red[w] = r0; red[4 + w] = r1; }
        __syncthreads();
        if (!t){
            meanb[bc] = (red[0] + red[1] + red[2] + red[3]) * (1.f / 4096.f);
            maxb[bc]  = fmaxf(fmaxf(red[4], red[5]), fmaxf(red[6], red[7]));
        }
    }
}

// K4: MERGED conv dispatch. Blocks 0..2047: 5x5 conv (ic-split halves);
// blocks 2048..4095: 3x3+1x1. r17: per ic, ALL row loads issued before any
// FMA (RA/RB arrays, unrolled -> static indices) so load latency hides under
// the first rows' FMA run.
#define OCB5 8
#define OCB3 4
__global__ __launch_bounds__(256, 4) void k_conv(const float* __restrict__ xtp,
                                                 const float* __restrict__ w1,
                                                 const float* __restrict__ w3,
                                                 const float* __restrict__ w5,
                                                 float* __restrict__ temp,
                                                 float* __restrict__ tempP,
                                                 float* __restrict__ tsum){
    int t = threadIdx.x;
    int k = t & 15, ty = t >> 4;
    int bid = blockIdx.x;

    if (bid < 2048){
        // ---- conv5: tile(4) x ocg(8) x bz(64 = b*2+half) ----
        int tile = bid & 3;
        int oc0 = ((bid >> 2) & 7) * OCB5;
        int bz = bid >> 5;
        int b = bz >> 1, half = bz & 1;
        int ic0 = half << 5;
        int y = (tile << 4) + ty;

        float a5[OCB5][4];
#pragma unroll
        for (int o = 0; o < OCB5; ++o)
#pragma unroll
            for (int px = 0; px < 4; ++px) a5[o][px] = 0.f;

        const float* plane = xtp + (size_t)(b * 64 + ic0) * PLANE + y * PCOLS + (k << 2);
        for (int ic = ic0; ic < ic0 + 32; ++ic, plane += PLANE){
            // issue ALL 10 row loads before any FMA
            float4 RA[5], RB[5];
#pragma unroll
            for (int dy = 0; dy < 5; ++dy){
                const float* rp = plane + dy * PCOLS;
                RA[dy] = *(const float4*)(rp);
                RB[dy] = *(const float4*)(rp + 4);
            }
#pragma unroll
            for (int dy = 0; dy < 5; ++dy){
                float v[8] = {RA[dy].x, RA[dy].y, RA[dy].z, RA[dy].w,
                              RB[dy].x, RB[dy].y, RB[dy].z, RB[dy].w};
#pragma unroll
                for (int o = 0; o < OCB5; ++o){
                    const float* W5r = w5 + (size_t)((oc0 + o) * 64 + ic) * 25 + dy * 5;
                    float w50 = W5r[0], w51 = W5r[1], w52 = W5r[2], w53 = W5r[3], w54 = W5r[4];
#pragma unroll
                    for (int px = 0; px < 4; ++px){
                        float acc = a5[o][px];
                        acc = fmaf(v[px + 0], w50, acc);
                        acc = fmaf(v[px + 1], w51, acc);
                        acc = fmaf(v[px + 2], w52, acc);
                        acc = fmaf(v[px + 3], w53, acc);
                        acc = fmaf(v[px + 4], w54, acc);
                        a5[o][px] = acc;
                    }
                }
            }
        }

        size_t pix = ((size_t)y << 6) + (k << 2);
        size_t bb = (size_t)b * 192;  // b*3*64
#pragma unroll
        for (int o = 0; o < OCB5; ++o){
            int oc = oc0 + o;
            float* dp = half ? (tempP + (((size_t)(b * 64 + oc)) << 12) + pix)
                             : (temp + (((bb + 128 + oc) << 12) + pix));
            *(float4*)dp = make_float4(a5[o][0], a5[o][1], a5[o][2], a5[o][3]);
        }
#pragma unroll
        for (int o = 0; o < OCB5; ++o){
            float s = (a5[o][0] + a5[o][1]) + (a5[o][2] + a5[o][3]);
            s = wave_sum(s);
            if (!(t & 63)) atomicAdd(&tsum[b * 384 + 128 + oc0 + o], s);
        }
    } else {
        // ---- conv31: tile(4) x ocg(16) x b(32) ----
        int idx = bid - 2048;
        int tile = idx & 3;
        int oc0 = ((idx >> 2) & 15) * OCB3;
        int b = idx >> 6;
        int y = (tile << 4) + ty;

        float a1[OCB3][4], a3[OCB3][4];
#pragma unroll
        for (int o = 0; o < OCB3; ++o)
#pragma unroll
            for (int px = 0; px < 4; ++px){ a1[o][px] = 0.f; a3[o][px] = 0.f; }

        const float* plane = xtp + (size_t)(b * 64) * PLANE + (y + 1) * PCOLS + (k << 2);
        for (int ic = 0; ic < 64; ++ic, plane += PLANE){
            float4 RA[3], RB[3];
#pragma unroll
            for (int dy = 0; dy < 3; ++dy){
                const float* rp = plane + dy * PCOLS;
                RA[dy] = *(const float4*)(rp);
                RB[dy] = *(const float4*)(rp + 4);
            }
#pragma unroll
            for (int dy = 0; dy < 3; ++dy){
                float v[8] = {RA[dy].x, RA[dy].y, RA[dy].z, RA[dy].w,
                              RB[dy].x, RB[dy].y, RB[dy].z, RB[dy].w};
#pragma unroll
                for (int o = 0; o < OCB3; ++o){
                    const float* W3r = w3 + (size_t)((oc0 + o) * 64 + ic) * 9 + dy * 3;
                    float w30 = W3r[0], w31 = W3r[1], w32 = W3r[2];
#pragma unroll
                    for (int px = 0; px < 4; ++px){
                        float acc = a3[o][px];
                        acc = fmaf(v[px + 1], w30, acc);
                        acc = fmaf(v[px + 2], w31, acc);
                        acc = fmaf(v[px + 3], w32, acc);
                        a3[o][px] = acc;
                    }
                }
                if (dy == 1){
#pragma unroll
                    for (int o = 0; o < OCB3; ++o){
                        float w10 = w1[(oc0 + o) * 64 + ic];
#pragma unroll
                        for (int px = 0; px < 4; ++px)
                            a1[o][px] = fmaf(v[px + 2], w10, a1[o][px]);
                    }
                }
            }
        }

        size_t pix = ((size_t)y << 6) + (k << 2);
        size_t bb = (size_t)b * 192;
#pragma unroll
        for (int o = 0; o < OCB3; ++o){
            int oc = oc0 + o;
            *(float4*)(temp + (((bb + oc) << 12) + pix))      = make_float4(a1[o][0], a1[o][1], a1[o][2], a1[o][3]);
            *(float4*)(temp + (((bb + 64 + oc) << 12) + pix)) = make_float4(a3[o][0], a3[o][1], a3[o][2], a3[o][3]);
        }
#pragma unroll
        for (int o = 0; o < OCB3; ++o){
            float s1 = (a1[o][0] + a1[o][1]) + (a1[o][2] + a1[o][3]);
            float s3 = (a3[o][0] + a3[o][1]) + (a3[o][2] + a3[o][3]);
            s1 = wave_sum(s1); s3 = wave_sum(s3);
            if (!(t & 63)){
                atomicAdd(&tsum[b * 384 + oc0 + o], s1);
                atomicAdd(&tsum[b * 384 + 64 + oc0 + o], s3);
            }
        }
    }
}

// K7: BN finalize (per-block from tsum/bnsq2d; block 0 publishes bn_m/bn_r
// for k_combine) + y = sigmoid(relu(tm @ w1.T) @ w2.T)
__global__ __launch_bounds__(384) void k_att(const float* __restrict__ tsum, const float* __restrict__ bnsq2d,
                                             float* __restrict__ bn_m, float* __restrict__ bn_r,
                                             const float* __restrict__ w1, const float* __restrict__ w2,
                                             float* __restrict__ yv){
    int b = blockIdx.x, t = threadIdx.x;
    __shared__ float tm[384], hid[48], bnm_s[128], bnr_s[128];
    if (t < 128){
        float S = 0.f, S2 = 0.f;
        for (int bb = 0; bb < 32; ++bb){
            S  += tsum[bb * 384 + 192 + t];
            S2 += bnsq2d[bb * 128 + t];
        }
        const float N = 131072.f;
        float m = S / N;
        float var = S2 / N - m * m;
        float rr = rsqrtf(var + 1e-5f);
        bnm_s[t] = m; bnr_s[t] = rr;
        if (b == 0){ bn_m[t] = m; bn_r[t] = rr; }
    }
    __syncthreads();
    float v = tsum[b * 384 + t] * (1.f / 4096.f);
    if (t >= 192 && t < 320){ int q = t - 192; v = (v - bnm_s[q]) * bnr_s[q]; }
    tm[t] = v; __syncthreads();
    if (t < 48){
        float a = 0.f; const float* wr = w1 + t * 384;
        for (int k = 0; k < 384; ++k) a = fmaf(wr[k], tm[k], a);
        hid[t] = fmaxf(a, 0.f);
    }
    __syncthreads();
    float o = 0.f; const float* wr = w2 + t * 48;
    for (int j = 0; j < 48; ++j) o = fmaf(wr[j], hid[j], o);
    yv[b * 384 + t] = 1.f / (1.f + expf(-o));
}

// K8: out = sum_op y_op * op_val (BN folded) (+x in round 2); scatter to
// h[:, idx[c]]. op2 = temp-half + tempP-half. Pools recomputed inline from
// the LDS-staged padded plane. Round 1: relu-stats epilogue -> meanb/maxb.
__global__ __launch_bounds__(256) void k_combine(const float* __restrict__ temp, const float* __restrict__ tempP,
                                                 const float* __restrict__ xtp,
                                                 const float* __restrict__ yv, const float* __restrict__ bn_m,
                                                 const float* __restrict__ bn_r, const int* __restrict__ idxp,
                                                 float* __restrict__ h, const float* __restrict__ xadd,
                                                 float* __restrict__ meanb, float* __restrict__ maxb){
    __shared__ float pl[PLANE];
    __shared__ float red[8];
    int c = blockIdx.x, b = blockIdx.y, t = threadIdx.x;
    const float* yb = yv + b * 384;
    float y0 = yb[c], y1 = yb[64 + c], y2 = yb[128 + c];
    float y3 = yb[192 + c], y4 = yb[256 + c], y5 = yb[320 + c];
    float m3 = bn_m[c], r3 = bn_r[c], m4 = bn_m[64 + c], r4 = bn_r[64 + c];
    float a3 = y3 * r3, c3 = -y3 * r3 * m3, a4 = y4 * r4, c4 = -y4 * r4 * m4;
    float bias = c3 + c4;
    size_t base = (((size_t)b * 192 + c) << 12);
    const float4* t0 = (const float4*)(temp + base);
    const float4* t1 = (const float4*)(temp + base + (64ull << 12));
    const float4* t2 = (const float4*)(temp + base + (128ull << 12));
    const float4* t2p = (const float4*)(tempP + (((size_t)(b * 64 + c)) << 12));
    const float4* p4 = (const float4*)(xtp + (size_t)(b * 64 + c) * PLANE);
    float4* pl4 = (float4*)pl;
    for (int i = t; i < PLANE / 4; i += 256) pl4[i] = p4[i];
    __syncthreads();

    int ch = idxp[c];
    size_t obase = ((size_t)(b * 256 + ch)) << 12;
    float4* o4 = (float4*)(h + obase);
    const float4* xa = xadd ? (const float4*)(xadd + obase) : (const float4*)nullptr;
    float sumr = 0.f, maxr = 0.f;
    for (int i = t; i < 1024; i += 256){
        float4 v0 = t0[i], v1 = t1[i], v2 = t2[i], v2b = t2p[i];
        v2.x += v2b.x; v2.y += v2b.y; v2.z += v2b.z; v2.w += v2b.w;
        float4 av4;
        if (xa) av4 = xa[i];
        int row = i >> 4, col0 = (i & 15) << 2;
        float res[4];
#pragma unroll
        for (int px = 0; px < 4; ++px){
            int x = col0 + px;
            float s = 0.f, m = 0.f;
#pragma unroll
            for (int dy = 0; dy < 3; ++dy){
                const float* q = pl + (row + 1 + dy) * PCOLS + x + 2;
                float a = q[-1], bb = q[0], cc = q[1];
                s += (a + bb) + cc;
                m = fmaxf(m, fmaxf(fmaxf(a, bb), cc));
            }
            int cy = min(row + 1, 63) - max(row - 1, 0) + 1;
            int cx = min(x + 1, 63) - max(x - 1, 0) + 1;
            float av = s / (float)(cy * cx);
            float v5 = pl[(row + 2) * PCOLS + x + 2];
            float tv0 = (px == 0) ? v0.x : (px == 1) ? v0.y : (px == 2) ? v0.z : v0.w;
            float tv1 = (px == 0) ? v1.x : (px == 1) ? v1.y : (px == 2) ? v1.z : v1.w;
            float tv2 = (px == 0) ? v2.x : (px == 1) ? v2.y : (px == 2) ? v2.z : v2.w;
            float r = y0 * tv0 + y1 * tv1 + y2 * tv2 + a3 * av + a4 * m + y5 * v5 + bias;
            sumr += fmaxf(r, 0.f);
            maxr = fmaxf(maxr, r);
            if (xa){
                float ax = (px == 0) ? av4.x : (px == 1) ? av4.y : (px == 2) ? av4.z : av4.w;
                r += ax;
            }
            res[px] = r;
        }
        o4[i] = make_float4(res[0], res[1], res[2], res[3]);
    }
    if (!xadd){
        float r0 = wave_sum(sumr), r1 = wave_max(maxr);
        int lane = t & 63, w = t >> 6;
        if (!lane){ red[w] = r0; red[4 + w] = r1; }
        __syncthreads();
        if (!t){
            meanb[b * 256 + ch] = (red[0] + red[1] + red[2] + red[3]) * (1.f / 4096.f);
            maxb[b * 256 + ch]  = fmaxf(fmaxf(fmaxf(red[4], red[5]), fmaxf(red[6], red[7])), 0.f);
        }
    }
}

extern "C" void kernel_launch(void* const* d_in, const int* in_sizes, int n_in,
                              void* d_out, int out_size, void* d_ws, size_t ws_size,
                              hipStream_t stream){
    const float* x = (const float*)d_in[0];
    float* h = (float*)d_out;                 // h buffer lives in d_out
    float* ws = (float*)d_ws;
    float* xtp   = ws;                        // 32*64*4624 = 9,469,952 floats (padded planes)
    float* temp  = ws + 9469952;              // 32*192*4096 = 25,165,824 floats (3 conv ops)
    float* tempP = ws + 9469952 + 25165824;   // 32*64*4096 = 8,388,608 floats (conv5 half-1)
    float* small = ws + 9469952 + 25165824 + 8388608;
    float* meanb = small;                     // 8192
    float* maxb  = small + 8192;              // 8192
    float* nl    = small + 16384;             // 8192
    float* tsum  = small + 24576;             // 12288
    float* bn_m  = small + 36864;             // 128
    float* bn_r  = small + 36992;             // 128
    float* yv    = small + 37120;             // 12288
    int*   idxp  = (int*)(small + 49408);     // 64
    int*   selp  = idxp + 64;                 // 256
    float* bnsq2d = small + 49792;            // 4096 floats [32][128], zeroed by k_topk

    // zero padded planes once (border rows/cols stay zero; interiors rewritten)
    hipMemsetAsync(xtp, 0, 9469952ull * 4, stream);

    for (int r = 0; r < 2; ++r){
        const float* ca_w1 = (const float*)d_in[2 + r * 7];
        const float* ca_w2 = (const float*)d_in[3 + r * 7];
        const float* w1    = (const float*)d_in[4 + r * 7];
        const float* w3    = (const float*)d_in[5 + r * 7];
        const float* w5    = (const float*)d_in[6 + r * 7];
        const float* a_w1  = (const float*)d_in[7 + r * 7];
        const float* a_w2  = (const float*)d_in[8 + r * 7];
        const float* src = (r == 0) ? x : h;
        const float* xadd = (r == 0) ? (const float*)nullptr : x;

        if (r == 0)
            hipLaunchKernelGGL(k_meanmax, dim3(8192), dim3(256), 0, stream, src, meanb, maxb);
        hipLaunchKernelGGL(k_nl,      dim3(32),   dim3(256), 0, stream, meanb, maxb, ca_w1, ca_w2, nl);
        hipLaunchKernelGGL(k_topk,    dim3(1),    dim3(256), 0, stream, nl, idxp, selp, tsum, bnsq2d);
        hipLaunchKernelGGL(k_scale,   dim3(8192), dim3(256), 0, stream, src, h, xtp, nl, selp, tsum, bnsq2d, xadd, meanb, maxb);
        hipLaunchKernelGGL(k_conv,    dim3(4096), dim3(256), 0, stream, xtp, w1, w3, w5, temp, tempP, tsum);
        hipLaunchKernelGGL(k_att,     dim3(32),   dim3(384), 0, stream, tsum, bnsq2d, bn_m, bn_r, a_w1, a_w2, yv);
        hipLaunchKernelGGL(k_combine, dim3(64, 32), dim3(256), 0, stream, temp, tempP, xtp, yv, bn_m, bn_r, idxp, h, xadd, meanb, maxb);
    }
}